// Round 3
// baseline (929.420 us; speedup 1.0000x reference)
//
#include <hip/hip_runtime.h>

// GRU, H=3, input (T,B,3) fp32, hidden (1,B,3).
// 4 lanes per chain (lane j owns hidden unit j, lane 3 mirrors unit 2),
// 16 chains/wave64, 256 blocks -> 1 wave per CU. Wall time = T x the carried
// dependency chain h(t)->h(t+1); everything else is hidden in stall slots.
//
// R3: minimal carried chain.
//  - weights pre-scaled into exp2 domain (sigmoid/tanh without scaling muls)
//  - x-side gate projections precomputed per 8-step batch (double-buffered
//    raw-x regs), so the chain starts at the 3-FMA h-dot seeded by gp[u]
//  - blend hung directly off rcp: u2=fma(2,R,h-1), n=fma(-2,R,1), h'=fma(z,u2,n)

#define PF 8

__device__ __forceinline__ float rcpf(float v) { return __builtin_amdgcn_rcpf(v); }
__device__ __forceinline__ float ex2(float v)  { return __builtin_amdgcn_exp2f(v); }

// Broadcast lane (quad_base + K) to all lanes of the quad via DPP quad_perm.
template <int CTRL>
__device__ __forceinline__ float quad_bcast(float v) {
    int i = __float_as_int(v);
    int r = __builtin_amdgcn_update_dpp(i, i, CTRL, 0xF, 0xF, true);
    return __int_as_float(r);
}

__global__ __launch_bounds__(64, 1)
void gru_seq_kernel(const float* __restrict__ x,    // (T,B,3)
                    const float* __restrict__ h0,   // (B,3)
                    const float* __restrict__ Wih,  // (9,3) row-major
                    const float* __restrict__ Whh,  // (9,3)
                    const float* __restrict__ bih,  // (9)
                    const float* __restrict__ bhh,  // (9)
                    float* __restrict__ out,        // (T,B,3) then (B,3)
                    int T, int B)
{
    const int lane  = threadIdx.x & 63;
    const int q     = lane & 3;
    const int j     = (q < 3) ? q : 2;           // lane 3 duplicates unit 2
    const int chain = blockIdx.x * 16 + (lane >> 2);
    if (chain >= B) return;

    const float NK = -1.4426950408889634f;       // -log2(e)  (sigmoid domain)
    const float K2 =  2.8853900817779268f;       // 2*log2(e) (tanh domain)

    // Hidden-side weights, pre-scaled.  r,z rows scaled by NK; n row by K2.
    const float whr0 = NK * Whh[(0 + j) * 3 + 0], whr1 = NK * Whh[(0 + j) * 3 + 1], whr2 = NK * Whh[(0 + j) * 3 + 2];
    const float whz0 = NK * Whh[(3 + j) * 3 + 0], whz1 = NK * Whh[(3 + j) * 3 + 1], whz2 = NK * Whh[(3 + j) * 3 + 2];
    const float whn0 = K2 * Whh[(6 + j) * 3 + 0], whn1 = K2 * Whh[(6 + j) * 3 + 1], whn2 = K2 * Whh[(6 + j) * 3 + 2];
    // Input-side weights for the batch transform, same scaling; biases folded.
    const float wir0 = NK * Wih[(0 + j) * 3 + 0], wir1 = NK * Wih[(0 + j) * 3 + 1], wir2 = NK * Wih[(0 + j) * 3 + 2];
    const float wiz0 = NK * Wih[(3 + j) * 3 + 0], wiz1 = NK * Wih[(3 + j) * 3 + 1], wiz2 = NK * Wih[(3 + j) * 3 + 2];
    const float win0 = K2 * Wih[(6 + j) * 3 + 0], win1 = K2 * Wih[(6 + j) * 3 + 1], win2 = K2 * Wih[(6 + j) * 3 + 2];
    const float br2  = NK * (bih[0 + j] + bhh[0 + j]);   // folded into gpr
    const float bz2  = NK * (bih[3 + j] + bhh[3 + j]);   // folded into gpz
    const float bni2 = K2 * bih[6 + j];                  // folded into gpn
    const float bnh2 = K2 * bhh[6 + j];                  // seeds the an2 h-dot

    // Initial hidden state.
    float hv0 = h0[chain * 3 + 0];
    float hv1 = h0[chain * 3 + 1];
    float hv2 = h0[chain * 3 + 2];
    float myh = (j == 0) ? hv0 : ((j == 1) ? hv1 : hv2);

    const int stride = B * 3;
    const int cb     = chain * 3;

    // Double-buffered raw x (8 steps each) + current batch's gate parts.
    float raw[2][PF][3];
    float gpr[PF], gpz[PF], gpn[PF];

    auto load_batch = [&](int buf, int t0) {
#pragma unroll
        for (int i = 0; i < PF; ++i) {
            int tt = t0 + i; if (tt > T - 1) tt = T - 1;     // clamp tail
            const float* p = x + (size_t)(cb + tt * stride);
            raw[buf][i][0] = p[0]; raw[buf][i][1] = p[1]; raw[buf][i][2] = p[2];
        }
    };
    auto transform = [&](int buf) {
#pragma unroll
        for (int i = 0; i < PF; ++i) {
            float x0 = raw[buf][i][0], x1 = raw[buf][i][1], x2 = raw[buf][i][2];
            gpr[i] = fmaf(wir0, x0, fmaf(wir1, x1, fmaf(wir2, x2, br2)));
            gpz[i] = fmaf(wiz0, x0, fmaf(wiz1, x1, fmaf(wiz2, x2, bz2)));
            gpn[i] = fmaf(win0, x0, fmaf(win1, x1, fmaf(win2, x2, bni2)));
        }
    };

    int o_off = cb + j;

    auto step = [&](int u) {
        // Carried chain: dpp -> 3 FMA -> exp2 -> add -> rcp -> fma -> exp2
        //                -> add -> rcp -> fma -> fma
        float hr  = fmaf(whr0, hv0, fmaf(whr1, hv1, fmaf(whr2, hv2, gpr[u])));
        float hz  = fmaf(whz0, hv0, fmaf(whz1, hv1, fmaf(whz2, hv2, gpz[u])));
        float an2 = fmaf(whn0, hv0, fmaf(whn1, hv1, fmaf(whn2, hv2, bnh2)));
        float hm1 = myh - 1.0f;                    // off-path (parallel w/ dots)
        float r   = rcpf(1.0f + ex2(hr));          // sigmoid, pre-scaled domain
        float z   = rcpf(1.0f + ex2(hz));          // off-path vs n (has slack)
        float y2  = fmaf(r, an2, gpn[u]);          // 2*log2e*(ani + r*anh)
        float R   = rcpf(ex2(y2) + 1.0f);
        float n   = fmaf(-2.0f, R, 1.0f);          // tanh
        float u2  = fmaf(2.0f, R, hm1);            // h - n
        myh = fmaf(z, u2, n);                      // (1-z)*n + z*h

        out[o_off] = myh; o_off += stride;         // off-path

        hv0 = quad_bcast<0x00>(myh);
        hv1 = quad_bcast<0x55>(myh);
        hv2 = quad_bcast<0xAA>(myh);
    };

    // Pipeline prologue: batch0 loaded+transformed, batch1 in flight.
    load_batch(0, 0);
    load_batch(1, PF);
    transform(0);
    int buf  = 1;        // raw[buf] = next batch's data (in flight or done)
    int pf_t = 2 * PF;   // base t of the next batch to issue

    const int nb = T / PF;
    for (int kb = 0; kb < nb; ++kb) {
        load_batch(buf ^ 1, pf_t);   // issue loads for batch kb+2
        pf_t += PF;
#pragma unroll
        for (int u = 0; u < PF; ++u) step(u);
        transform(buf);              // parts for batch kb+1 (loads long done)
        buf ^= 1;
    }
    // Remainder steps (T % PF != 0): direct load+transform, off the fast path.
    for (int t = nb * PF; t < T; ++t) {
        const float* p = x + (size_t)(cb + t * stride);
        float x0 = p[0], x1 = p[1], x2 = p[2];
        gpr[0] = fmaf(wir0, x0, fmaf(wir1, x1, fmaf(wir2, x2, br2)));
        gpz[0] = fmaf(wiz0, x0, fmaf(wiz1, x1, fmaf(wiz2, x2, bz2)));
        gpn[0] = fmaf(win0, x0, fmaf(win1, x1, fmaf(win2, x2, bni2)));
        step(0);
    }

    // h_last tail: d_out = [output (T*B*3) | h_last (B*3)].
    out[o_off] = myh;
}

extern "C" void kernel_launch(void* const* d_in, const int* in_sizes, int n_in,
                              void* d_out, int out_size, void* d_ws, size_t ws_size,
                              hipStream_t stream) {
    const float* x   = (const float*)d_in[0];
    const float* h0  = (const float*)d_in[1];
    const float* Wih = (const float*)d_in[2];
    const float* Whh = (const float*)d_in[3];
    const float* bih = (const float*)d_in[4];
    const float* bhh = (const float*)d_in[5];
    float* out = (float*)d_out;

    const int B = in_sizes[1] / 3;              // hidden is (1,B,3)
    const int T = in_sizes[0] / in_sizes[1];    // input is (T,B,3)

    const int grid = (B + 15) / 16;             // 16 chains per 64-thread block
    gru_seq_kernel<<<grid, 64, 0, stream>>>(x, h0, Wih, Whh, bih, bhh, out, T, B);
}

// Round 4
// 396.761 us; speedup vs baseline: 2.3425x; 2.3425x over previous
//
#include <hip/hip_runtime.h>

// GRU, H=3, input (T,B,3) fp32, hidden (1,B,3).
// 4 lanes per chain (lane j owns hidden unit j, lane 3 mirrors unit 2),
// 16 chains/wave64, 256 blocks -> 1 wave per CU. Wall time = T x the carried
// dependency chain h(t)->h(t+1); everything else must hide in stall slots.
//
// R4 = R3's short chain + R2's static-index ring (R3 regressed because the
// dynamically-indexed raw[buf][..] array spilled to scratch; all arrays here
// are indexed only by fully-unrolled induction vars -> stay in VGPRs).
//
// Carried chain per step:
//   dpp -> fma x3 -> exp2 -> add -> rcp -> fma -> exp2 -> add -> rcp -> fma -> fma

#define PF 8

__device__ __forceinline__ float rcpf(float v) { return __builtin_amdgcn_rcpf(v); }
__device__ __forceinline__ float ex2(float v)  { return __builtin_amdgcn_exp2f(v); }

// Broadcast lane (quad_base + K) to all lanes of the quad via DPP quad_perm.
template <int CTRL>
__device__ __forceinline__ float quad_bcast(float v) {
    int i = __float_as_int(v);
    int r = __builtin_amdgcn_update_dpp(i, i, CTRL, 0xF, 0xF, true);
    return __int_as_float(r);
}

__global__ __launch_bounds__(64, 1)
void gru_seq_kernel(const float* __restrict__ x,    // (T,B,3)
                    const float* __restrict__ h0,   // (B,3)
                    const float* __restrict__ Wih,  // (9,3) row-major
                    const float* __restrict__ Whh,  // (9,3)
                    const float* __restrict__ bih,  // (9)
                    const float* __restrict__ bhh,  // (9)
                    float* __restrict__ out,        // (T,B,3) then (B,3)
                    int T, int B)
{
    const int lane  = threadIdx.x & 63;
    const int q     = lane & 3;
    const int j     = (q < 3) ? q : 2;           // lane 3 duplicates unit 2
    const int chain = blockIdx.x * 16 + (lane >> 2);
    if (chain >= B) return;

    const float NK = -1.4426950408889634f;       // -log2(e)  (sigmoid domain)
    const float K2 =  2.8853900817779268f;       // 2*log2(e) (tanh domain)

    // Hidden-side weights, pre-scaled: r,z rows by NK; n row by K2.
    const float whr0 = NK * Whh[(0 + j) * 3 + 0], whr1 = NK * Whh[(0 + j) * 3 + 1], whr2 = NK * Whh[(0 + j) * 3 + 2];
    const float whz0 = NK * Whh[(3 + j) * 3 + 0], whz1 = NK * Whh[(3 + j) * 3 + 1], whz2 = NK * Whh[(3 + j) * 3 + 2];
    const float whn0 = K2 * Whh[(6 + j) * 3 + 0], whn1 = K2 * Whh[(6 + j) * 3 + 1], whn2 = K2 * Whh[(6 + j) * 3 + 2];
    // Input-side weights, same scaling; biases folded into projections.
    const float wir0 = NK * Wih[(0 + j) * 3 + 0], wir1 = NK * Wih[(0 + j) * 3 + 1], wir2 = NK * Wih[(0 + j) * 3 + 2];
    const float wiz0 = NK * Wih[(3 + j) * 3 + 0], wiz1 = NK * Wih[(3 + j) * 3 + 1], wiz2 = NK * Wih[(3 + j) * 3 + 2];
    const float win0 = K2 * Wih[(6 + j) * 3 + 0], win1 = K2 * Wih[(6 + j) * 3 + 1], win2 = K2 * Wih[(6 + j) * 3 + 2];
    const float br2  = NK * (bih[0 + j] + bhh[0 + j]);
    const float bz2  = NK * (bih[3 + j] + bhh[3 + j]);
    const float bni2 = K2 * bih[6 + j];
    const float bnh2 = K2 * bhh[6 + j];          // seeds the an2 h-dot

    // Initial hidden state.
    float hv0 = h0[chain * 3 + 0];
    float hv1 = h0[chain * 3 + 1];
    float hv2 = h0[chain * 3 + 2];
    float myh = (j == 0) ? hv0 : ((j == 1) ? hv1 : hv2);
    float hm1 = myh - 1.0f;

    const int stride = B * 3;
    const int cb     = chain * 3;
    const int tmax_off = cb + (T - 1) * stride;  // clamp for tail prefetch

    // Rings — ONLY constant indices after unroll (never a runtime variable).
    float xb[PF][3];                             // raw x, PF steps ahead
    float gpr[PF], gpz[PF], gpn[PF];             // projections for current PF steps

    // ---- Prologue ----
#pragma unroll
    for (int i = 0; i < PF; ++i) {               // xb[i] = x[i]
        const float* p = x + (size_t)(cb + i * stride);
        xb[i][0] = p[0]; xb[i][1] = p[1]; xb[i][2] = p[2];
    }
#pragma unroll
    for (int i = 0; i < PF; ++i) {               // gp[i] = proj(x[i])
        float x0 = xb[i][0], x1 = xb[i][1], x2 = xb[i][2];
        gpr[i] = fmaf(wir0, x0, fmaf(wir1, x1, fmaf(wir2, x2, br2)));
        gpz[i] = fmaf(wiz0, x0, fmaf(wiz1, x1, fmaf(wiz2, x2, bz2)));
        gpn[i] = fmaf(win0, x0, fmaf(win1, x1, fmaf(win2, x2, bni2)));
    }
#pragma unroll
    for (int i = 0; i < PF; ++i) {               // xb[i] = x[PF+i]
        int off = cb + (PF + i) * stride; if (off > tmax_off) off = tmax_off;
        const float* p = x + (size_t)off;
        xb[i][0] = p[0]; xb[i][1] = p[1]; xb[i][2] = p[2];
    }

    int o_off  = cb + j;                         // store offset for t=0
    int pf_off = cb + 2 * PF * stride;           // next raw-x offset to load

    // Carried-chain step: consumes projection values, updates h state.
    auto core = [&](float gr, float gz, float gn) {
        float hr  = fmaf(whr0, hv0, fmaf(whr1, hv1, fmaf(whr2, hv2, gr)));
        float hz  = fmaf(whz0, hv0, fmaf(whz1, hv1, fmaf(whz2, hv2, gz)));
        float an2 = fmaf(whn0, hv0, fmaf(whn1, hv1, fmaf(whn2, hv2, bnh2)));
        float r   = rcpf(1.0f + ex2(hr));        // sigmoid (pre-scaled)
        float z   = rcpf(1.0f + ex2(hz));        // off-path vs n (has slack)
        float y2  = fmaf(r, an2, gn);            // 2*log2e*(ani + r*anh)
        float R   = rcpf(ex2(y2) + 1.0f);
        float n   = fmaf(-2.0f, R, 1.0f);        // tanh
        float u2  = fmaf(2.0f, R, hm1);          // h - n
        myh = fmaf(z, u2, n);                    // (1-z)*n + z*h

        out[o_off] = myh; o_off += stride;       // off-path
        hm1 = myh - 1.0f;                        // off-path (parallel w/ dpp)
        hv0 = quad_bcast<0x00>(myh);
        hv1 = quad_bcast<0x55>(myh);
        hv2 = quad_bcast<0xAA>(myh);
    };

    const int nb = T / PF;
    for (int kb = 0; kb < nb; ++kb) {
#pragma unroll
        for (int u = 0; u < PF; ++u) {
            core(gpr[u], gpz[u], gpn[u]);
            // Refill slot u: project x[t+PF] (loaded PF steps ago), then
            // issue the load of x[t+2PF] into the freed slot. All indices
            // are compile-time constants -> everything stays in VGPRs.
            float x0 = xb[u][0], x1 = xb[u][1], x2 = xb[u][2];
            gpr[u] = fmaf(wir0, x0, fmaf(wir1, x1, fmaf(wir2, x2, br2)));
            gpz[u] = fmaf(wiz0, x0, fmaf(wiz1, x1, fmaf(wiz2, x2, bz2)));
            gpn[u] = fmaf(win0, x0, fmaf(win1, x1, fmaf(win2, x2, bni2)));
            int off = pf_off; if (off > tmax_off) off = tmax_off;
            const float* p = x + (size_t)off;
            xb[u][0] = p[0]; xb[u][1] = p[1]; xb[u][2] = p[2];
            pf_off += stride;
        }
    }
    // Remainder (T % PF): straight-line, off the fast path.
    for (int t = nb * PF; t < T; ++t) {
        const float* p = x + (size_t)(cb + t * stride);
        float x0 = p[0], x1 = p[1], x2 = p[2];
        float gr = fmaf(wir0, x0, fmaf(wir1, x1, fmaf(wir2, x2, br2)));
        float gz = fmaf(wiz0, x0, fmaf(wiz1, x1, fmaf(wiz2, x2, bz2)));
        float gn = fmaf(win0, x0, fmaf(win1, x1, fmaf(win2, x2, bni2)));
        core(gr, gz, gn);
    }

    // h_last tail: d_out = [output (T*B*3) | h_last (B*3)].
    out[o_off] = myh;
}

extern "C" void kernel_launch(void* const* d_in, const int* in_sizes, int n_in,
                              void* d_out, int out_size, void* d_ws, size_t ws_size,
                              hipStream_t stream) {
    const float* x   = (const float*)d_in[0];
    const float* h0  = (const float*)d_in[1];
    const float* Wih = (const float*)d_in[2];
    const float* Whh = (const float*)d_in[3];
    const float* bih = (const float*)d_in[4];
    const float* bhh = (const float*)d_in[5];
    float* out = (float*)d_out;

    const int B = in_sizes[1] / 3;              // hidden is (1,B,3)
    const int T = in_sizes[0] / in_sizes[1];    // input is (T,B,3)

    const int grid = (B + 15) / 16;             // 16 chains per 64-thread block
    gru_seq_kernel<<<grid, 64, 0, stream>>>(x, h0, Wih, Whh, bih, bhh, out, T, B);
}